// Round 6
// 616.913 us; speedup vs baseline: 1.0127x; 1.0127x over previous
//
#include <hip/hip_runtime.h>
#include <stdint.h>

// ---------------------------------------------------------------------------
// cha_third_conv: polynomial channel expansion (L=8, orders 1..3) + 1x1 conv.
// GEMM view: M=B*H*W=12544, N=256, K=32 groups * 164 feats (padded to 192).
// BISECT ROUND (packed-write isolation): round-0 kernel (PASSED, 625us)
// verbatim — ldsX staging, runtime pm2/pcm LDS tables, same feature
// expressions, 3 barriers/group, same MFMA core/epilogue/prep_w/grid —
// with EXACTLY ONE delta: the feature loop is regrouped into 8-feature
// chunks per thread (part0: feats 0..87, part1: 88..167) and each chunk is
// written with ONE uint4 (ds_write_b128) instead of 8 scalar ds_write_b16.
// Feature values and destinations are bit-identical to round 0.
//   PASS  -> packed LDS writes exonerated; register-x/featk indicted (next).
//   FAIL  -> packed LDS writes indicted.
// ---------------------------------------------------------------------------

typedef short bf16x8 __attribute__((ext_vector_type(8)));
typedef float f32x4  __attribute__((ext_vector_type(4)));

__device__ __forceinline__ unsigned f2bf(float f) {
  unsigned u = __float_as_uint(f);
  return ((u + 0x7FFFu + ((u >> 16) & 1u)) >> 16) & 0xFFFFu;   // RTNE
}

#define ROW_S 200   // A-tile row stride in shorts (400 B) — round-0 layout

// ---------------------------------------------------------------------------
// Prep: verbatim round 0 (passed). weight (256 x 5248 fp32) -> bf16, padded
// 164->192/group, B-swizzled: ws[((sg*4+q)*256+n)*8+j] = w[n][g*164+s*32+q*8+j].
// ---------------------------------------------------------------------------
__global__ void prep_w(const float* __restrict__ w, short* __restrict__ wout) {
  int e = blockIdx.x * 256 + threadIdx.x;   // < 1,572,864
  int j  = e & 7;
  int n  = (e >> 3) & 255;
  int t2 = e >> 11;
  int q  = t2 & 3;
  int sg = t2 >> 2;                         // 0..191
  int g  = sg / 6;
  int s  = sg - g * 6;
  int kk = s * 32 + q * 8 + j;              // 0..191 (reference order + pad)
  float val = (kk < 164) ? w[n * 5248 + g * 164 + kk] : 0.0f;
  wout[e] = (short)f2bf(val);
}

// ---------------------------------------------------------------------------
// Main fused kernel — round-0 skeleton. Grid: (98 M-tiles of 128) x (4 N-tiles
// of 64). Block: 256 threads = 4 waves in 2(M) x 2(N); wave tile M64 x N32.
// Staging: ldsX + runtime tables + SAME per-feature expressions as round 0,
// but grouped 8-at-a-time into registers and sunk via one uint4 per chunk.
// ---------------------------------------------------------------------------
__global__ __launch_bounds__(256, 2) void poly_gemm(
    const float* __restrict__ in, const short* __restrict__ wbf,
    const float* __restrict__ bias, const int* __restrict__ pm2,
    const int* __restrict__ pcm, float* __restrict__ out) {
  __shared__ __align__(16) short ldsA[128 * ROW_S];   // 51,200 B
  __shared__ float ldsX[128 * 9];                     // 4,608 B (stride 9: banks)
  __shared__ int tPa[36], tPb[36], tTc[120], tTp[120];

  const int tid  = threadIdx.x;
  const int m0   = blockIdx.x * 128;
  const int n0   = blockIdx.y * 64;
  const int lane = tid & 63;
  const int wave = tid >> 6;
  const int wm   = wave >> 1;       // M half
  const int wn   = wave & 1;        // N half
  const int quad = lane >> 4;
  const int l16  = lane & 15;

  // one-time init: runtime monomial tables + A-tile k-pad (shorts 164..199)
  if (tid < 36)  { tPa[tid] = pm2[2 * tid]; tPb[tid] = pm2[2 * tid + 1]; }
  if (tid < 120) { tTc[tid] = pcm[2 * tid]; tTp[tid] = pcm[2 * tid + 1]; }
  for (int i = tid; i < 128 * 36; i += 256) {
    int rr = i / 36, ss = 164 + (i - rr * 36);
    ldsA[rr * ROW_S + ss] = 0;
  }

  f32x4 acc[4][2];
#pragma unroll
  for (int mf = 0; mf < 4; mf++)
#pragma unroll
    for (int nf = 0; nf < 2; nf++) acc[mf][nf] = (f32x4){0.f, 0.f, 0.f, 0.f};

  const int pix  = tid & 127;
  const int part = tid >> 7;
  const int mg   = m0 + pix;
  const unsigned bb = (unsigned)mg / 3136u;
  const unsigned pp = (unsigned)mg - bb * 3136u;
  const float* xbase = in + (size_t)bb * 802816u + pp;

  for (int g = 0; g < 32; ++g) {
    __syncthreads();   // (a) previous iteration's MFMA reads done (or init done)

    // stage A: per-pixel x[8] (this group's channels) into LDS — round-0 verbatim
    if (part == 0) {
#pragma unroll
      for (int c = 0; c < 8; ++c) ldsX[pix * 9 + c] = xbase[(g * 8 + c) * 3136];
    }
    __syncthreads();

    // stage B: same feature expressions as round 0, regrouped into 8-feature
    // register packs, one uint4 LDS store per chunk.
    {
      short* arow = &ldsA[pix * ROW_S];
      const float* xrow = &ldsX[pix * 9];
      const int chLo = part ? 11 : 0;       // part0: chunks 0..10 (feats 0..87)
      const int chHi = part ? 21 : 11;      // part1: chunks 11..20 (feats 88..167)
      for (int ch = chLo; ch < chHi; ++ch) {
        unsigned u0 = 0, u1 = 0, u2 = 0, u3 = 0;
#pragma unroll
        for (int j = 0; j < 8; ++j) {
          int k = ch * 8 + j;
          float f;
          if (k < 8) {
            f = xrow[k];                                   // linear
          } else if (k < 44) {
            int rr = k - 8;                                // pm2 pair
            f = xrow[tPa[rr]] * xrow[tPb[rr]];
          } else if (k < 164) {
            int rr = k - 44;                               // pcm triple: x * x2
            int pos = tTp[rr];
            float p = xrow[tPa[pos]] * xrow[tPb[pos]];     // x2 (same fp32 round)
            f = xrow[tTc[rr]] * p;
          } else {
            f = 0.0f;                                      // pad 164..167
          }
          unsigned b = f2bf(f) << ((j & 1) * 16);
          if (j < 2) u0 |= b; else if (j < 4) u1 |= b;
          else if (j < 6) u2 |= b; else u3 |= b;
        }
        uint4 v; v.x = u0; v.y = u1; v.z = u2; v.w = u3;
        *reinterpret_cast<uint4*>(arow + (ch << 3)) = v;   // 16B aligned
      }
    }
    __syncthreads();   // (b) A-tile ready

    // MFMA phase — round-0 verbatim
#pragma unroll
    for (int ks = 0; ks < 6; ++ks) {
      bf16x8 af[4];
#pragma unroll
      for (int mf = 0; mf < 4; mf++) {
        int row = wm * 64 + mf * 16 + l16;
        af[mf] = *(const bf16x8*)(ldsA + row * ROW_S + ks * 32 + quad * 8);
      }
      bf16x8 bfr[2];
      const int sg = g * 6 + ks;
#pragma unroll
      for (int nf = 0; nf < 2; nf++) {
        int n = n0 + wn * 32 + nf * 16 + l16;
        bfr[nf] = *(const bf16x8*)(wbf + (((size_t)(sg * 4 + quad) * 256 + n) << 3));
      }
#pragma unroll
      for (int mf = 0; mf < 4; mf++)
#pragma unroll
        for (int nf = 0; nf < 2; nf++)
          acc[mf][nf] = __builtin_amdgcn_mfma_f32_16x16x32_bf16(af[mf], bfr[nf], acc[mf][nf], 0, 0, 0);
    }
  }

  // epilogue — round-0 verbatim: D col = lane&15 (out ch), row = quad*4 + r
#pragma unroll
  for (int nf = 0; nf < 2; nf++) {
    const int col = n0 + wn * 32 + nf * 16 + l16;
    const float bv = bias[col];
#pragma unroll
    for (int mf = 0; mf < 4; mf++) {
#pragma unroll
      for (int r = 0; r < 4; r++) {
        int mg2 = m0 + wm * 64 + mf * 16 + quad * 4 + r;
        unsigned b2 = (unsigned)mg2 / 3136u;
        unsigned p2 = (unsigned)mg2 - b2 * 3136u;
        out[(size_t)b2 * 802816u + (size_t)col * 3136u + p2] = acc[mf][nf][r] + bv;
      }
    }
  }
}

extern "C" void kernel_launch(void* const* d_in, const int* in_sizes, int n_in,
                              void* d_out, int out_size, void* d_ws, size_t ws_size,
                              hipStream_t stream) {
  (void)in_sizes; (void)n_in; (void)out_size; (void)ws_size;
  const float* inp  = (const float*)d_in[0];
  const float* w    = (const float*)d_in[1];
  const float* bias = (const float*)d_in[2];
  const int*   pm2  = (const int*)d_in[3];
  const int*   pcm  = (const int*)d_in[4];
  short* wbf = (short*)d_ws;            // 3,145,728 B used

  prep_w<<<6144, 256, 0, stream>>>(w, wbf);
  poly_gemm<<<dim3(98, 4), 256, 0, stream>>>(inp, wbf, bias, pm2, pcm, (float*)d_out);
}

// Round 7
// 248.420 us; speedup vs baseline: 2.5149x; 2.4833x over previous
//
#include <hip/hip_runtime.h>
#include <stdint.h>

// ---------------------------------------------------------------------------
// cha_third_conv: polynomial channel expansion (L=8, orders 1..3) + 1x1 conv.
// GEMM view: M=B*H*W=12544, N=256, K=32 groups * 164 feats (padded to 192).
// Round 7: built strictly on the round-6 PASSING base (runtime tables, LDS
// xrow reads, packed uint4 chunk writes, M128xN64, same MFMA core/epilogue/
// prep_w). One structural change to kill the LDS-latency exposure in stage-B:
//   1) init-time DEREFERENCED+PACKED tables: pAB[q]=a|b<<8 (pairs),
//      tABC[r]=c0|a<<8|b<<16 (triples, pm2[pos] resolved once) — 1 uniform
//      table read per feature instead of a 2-4 deep chain; values identical.
//   2) stage-B fully static: template featv<K>/emit_chunk<CH> — branch-free,
//      ~100 independent read->mul->cvt chains per part for the scheduler.
//   3) double-buffered ldsX + issue-early/write-late x prefetch (T14):
//      2 barriers/group (was 3); global latency hides under stage-B compute.
// Feature values, order, rounding: bit-identical to round 6 (passed, 0.0625).
// ---------------------------------------------------------------------------

typedef short bf16x8 __attribute__((ext_vector_type(8)));
typedef float f32x4  __attribute__((ext_vector_type(4)));

__device__ __forceinline__ unsigned f2bf(float f) {
  unsigned u = __float_as_uint(f);
  return ((u + 0x7FFFu + ((u >> 16) & 1u)) >> 16) & 0xFFFFu;   // RTNE
}
__device__ __forceinline__ unsigned pk2(float lo, float hi) {
  return f2bf(lo) | (f2bf(hi) << 16);
}

#define ROW_S 200   // A-tile row stride in shorts (400 B) — round-0/6 layout

// ---------------------------------------------------------------------------
// featv<K>: feature K from xrow (runtime LDS floats) + packed runtime tables.
// Same expressions and fp32 rounding as round 6's loop:
//   pairs:  xrow[a] * xrow[b]
//   triples: xrow[c0] * (xrow[a] * xrow[b])   (pair product rounds first)
// ---------------------------------------------------------------------------
template <int K>
__device__ __forceinline__ float featv(const float* __restrict__ xrow,
                                       const int* __restrict__ pAB,
                                       const int* __restrict__ tABC) {
  if constexpr (K < 8) {
    return xrow[K];
  } else if constexpr (K < 44) {
    int ab = pAB[K - 8];                        // a | b<<8 (uniform -> broadcast)
    return xrow[ab & 255] * xrow[(ab >> 8) & 255];
  } else if constexpr (K < 164) {
    int abc = tABC[K - 44];                     // c0 | a<<8 | b<<16
    float p = xrow[(abc >> 8) & 255] * xrow[(abc >> 16) & 255];
    return xrow[abc & 255] * p;
  } else {
    return 0.0f;                                // pad 164..167
  }
}

// one 16B chunk = features 8*CH .. 8*CH+7 at linear chunk position CH
template <int CH>
__device__ __forceinline__ void emit_chunk(const float* __restrict__ xrow,
                                           const int* __restrict__ pAB,
                                           const int* __restrict__ tABC,
                                           short* __restrict__ arow) {
  unsigned u0 = pk2(featv<CH * 8 + 0>(xrow, pAB, tABC), featv<CH * 8 + 1>(xrow, pAB, tABC));
  unsigned u1 = pk2(featv<CH * 8 + 2>(xrow, pAB, tABC), featv<CH * 8 + 3>(xrow, pAB, tABC));
  unsigned u2 = pk2(featv<CH * 8 + 4>(xrow, pAB, tABC), featv<CH * 8 + 5>(xrow, pAB, tABC));
  unsigned u3 = pk2(featv<CH * 8 + 6>(xrow, pAB, tABC), featv<CH * 8 + 7>(xrow, pAB, tABC));
  uint4 v; v.x = u0; v.y = u1; v.z = u2; v.w = u3;
  *reinterpret_cast<uint4*>(arow + (CH << 3)) = v;   // 16B aligned
}

// part0: chunks 0..10 (feats 0..87), part1: chunks 11..20 (88..167) — as r6
__device__ __forceinline__ void stage_part0(const float* xrow, const int* pAB,
                                            const int* tABC, short* arow) {
  emit_chunk<0>(xrow, pAB, tABC, arow);
  emit_chunk<1>(xrow, pAB, tABC, arow);
  emit_chunk<2>(xrow, pAB, tABC, arow);
  emit_chunk<3>(xrow, pAB, tABC, arow);
  emit_chunk<4>(xrow, pAB, tABC, arow);
  emit_chunk<5>(xrow, pAB, tABC, arow);
  emit_chunk<6>(xrow, pAB, tABC, arow);
  emit_chunk<7>(xrow, pAB, tABC, arow);
  emit_chunk<8>(xrow, pAB, tABC, arow);
  emit_chunk<9>(xrow, pAB, tABC, arow);
  emit_chunk<10>(xrow, pAB, tABC, arow);
}
__device__ __forceinline__ void stage_part1(const float* xrow, const int* pAB,
                                            const int* tABC, short* arow) {
  emit_chunk<11>(xrow, pAB, tABC, arow);
  emit_chunk<12>(xrow, pAB, tABC, arow);
  emit_chunk<13>(xrow, pAB, tABC, arow);
  emit_chunk<14>(xrow, pAB, tABC, arow);
  emit_chunk<15>(xrow, pAB, tABC, arow);
  emit_chunk<16>(xrow, pAB, tABC, arow);
  emit_chunk<17>(xrow, pAB, tABC, arow);
  emit_chunk<18>(xrow, pAB, tABC, arow);
  emit_chunk<19>(xrow, pAB, tABC, arow);
  emit_chunk<20>(xrow, pAB, tABC, arow);
}

// ---------------------------------------------------------------------------
// Prep: verbatim round 0/6 (passed). weight (256 x 5248 fp32) -> bf16, padded
// 164->192/group, B-swizzled: ws[((sg*4+q)*256+n)*8+j] = w[n][g*164+s*32+q*8+j].
// ---------------------------------------------------------------------------
__global__ void prep_w(const float* __restrict__ w, short* __restrict__ wout) {
  int e = blockIdx.x * 256 + threadIdx.x;   // < 1,572,864
  int j  = e & 7;
  int n  = (e >> 3) & 255;
  int t2 = e >> 11;
  int q  = t2 & 3;
  int sg = t2 >> 2;                         // 0..191
  int g  = sg / 6;
  int s  = sg - g * 6;
  int kk = s * 32 + q * 8 + j;              // 0..191 (reference order + pad)
  float val = (kk < 164) ? w[n * 5248 + g * 164 + kk] : 0.0f;
  wout[e] = (short)f2bf(val);
}

// ---------------------------------------------------------------------------
// Main fused kernel — round-6 skeleton. Grid: (98 M-tiles of 128) x (4 N-tiles
// of 64). Block: 256 threads = 4 waves in 2(M) x 2(N); wave tile M64 x N32.
// Per group: {stage-B (static, from ldsX[g&1]) | x-prefetch issue/write} ->
// barrier -> MFMA -> barrier.  2 barriers/group.
// ---------------------------------------------------------------------------
__global__ __launch_bounds__(256, 2) void poly_gemm(
    const float* __restrict__ in, const short* __restrict__ wbf,
    const float* __restrict__ bias, const int* __restrict__ pm2,
    const int* __restrict__ pcm, float* __restrict__ out) {
  __shared__ __align__(16) short ldsA[128 * ROW_S];   // 51,200 B
  __shared__ float ldsX[2][128 * 9];                  // 9,216 B (stride 9)
  __shared__ int pAB[36];                             // a | b<<8
  __shared__ int tABC[120];                           // c0 | a<<8 | b<<16

  const int tid  = threadIdx.x;
  const int m0   = blockIdx.x * 128;
  const int n0   = blockIdx.y * 64;
  const int lane = tid & 63;
  const int wave = tid >> 6;
  const int wm   = wave >> 1;       // M half
  const int wn   = wave & 1;        // N half
  const int quad = lane >> 4;
  const int l16  = lane & 15;

  // one-time init: packed+dereferenced tables + A-tile k-pad (shorts 164..199)
  if (tid < 36)  pAB[tid] = pm2[2 * tid] | (pm2[2 * tid + 1] << 8);
  if (tid < 120) {
    int pos = pcm[2 * tid + 1];
    tABC[tid] = pcm[2 * tid] | (pm2[2 * pos] << 8) | (pm2[2 * pos + 1] << 16);
  }
  for (int i = tid; i < 128 * 36; i += 256) {
    int rr = i / 36, ss = 164 + (i - rr * 36);
    ldsA[rr * ROW_S + ss] = 0;
  }

  f32x4 acc[4][2];
#pragma unroll
  for (int mf = 0; mf < 4; mf++)
#pragma unroll
    for (int nf = 0; nf < 2; nf++) acc[mf][nf] = (f32x4){0.f, 0.f, 0.f, 0.f};

  const int pix  = tid & 127;
  const int part = tid >> 7;
  const int mg   = m0 + pix;
  const unsigned bb = (unsigned)mg / 3136u;
  const unsigned pp = (unsigned)mg - bb * 3136u;
  const float* xbase = in + (size_t)bb * 802816u + pp;

  // prologue: group-0 x into ldsX[0]; barrier also covers table/pad init
  if (part == 0) {
#pragma unroll
    for (int c = 0; c < 8; ++c) ldsX[0][pix * 9 + c] = xbase[(size_t)c * 3136u];
  }
  __syncthreads();

  for (int g = 0; g < 32; ++g) {
    // issue next group's x loads EARLY (latency hides under stage-B compute)
    float xn[8];
    if (part == 0 && g < 31) {
      const float* xp = xbase + (size_t)((g + 1) * 8) * 3136u;
#pragma unroll
      for (int c = 0; c < 8; ++c) xn[c] = xp[(size_t)c * 3136u];
    }

    // stage-B: 164 features from ldsX[g&1], static unrolled, packed writes
    {
      const float* xrow = &ldsX[g & 1][pix * 9];
      short* arow = &ldsA[pix * ROW_S];
      if (part == 0) stage_part0(xrow, pAB, tABC, arow);
      else           stage_part1(xrow, pAB, tABC, arow);
    }

    // write-late: next group's x into the other ldsX buffer
    if (part == 0 && g < 31) {
#pragma unroll
      for (int c = 0; c < 8; ++c) ldsX[(g + 1) & 1][pix * 9 + c] = xn[c];
    }
    __syncthreads();   // (b) A-tile ready; ldsX[g+1] ready

    // MFMA phase — round-6 verbatim
#pragma unroll
    for (int ks = 0; ks < 6; ++ks) {
      bf16x8 af[4];
#pragma unroll
      for (int mf = 0; mf < 4; mf++) {
        int row = wm * 64 + mf * 16 + l16;
        af[mf] = *(const bf16x8*)(ldsA + row * ROW_S + ks * 32 + quad * 8);
      }
      bf16x8 bfr[2];
      const int sg = g * 6 + ks;
#pragma unroll
      for (int nf = 0; nf < 2; nf++) {
        int n = n0 + wn * 32 + nf * 16 + l16;
        bfr[nf] = *(const bf16x8*)(wbf + (((size_t)(sg * 4 + quad) * 256 + n) << 3));
      }
#pragma unroll
      for (int mf = 0; mf < 4; mf++)
#pragma unroll
        for (int nf = 0; nf < 2; nf++)
          acc[mf][nf] = __builtin_amdgcn_mfma_f32_16x16x32_bf16(af[mf], bfr[nf], acc[mf][nf], 0, 0, 0);
    }
    __syncthreads();   // (a) MFMA reads done before next stage-B overwrites
  }

  // epilogue — round-6 verbatim: D col = lane&15 (out ch), row = quad*4 + r
#pragma unroll
  for (int nf = 0; nf < 2; nf++) {
    const int col = n0 + wn * 32 + nf * 16 + l16;
    const float bv = bias[col];
#pragma unroll
    for (int mf = 0; mf < 4; mf++) {
#pragma unroll
      for (int r = 0; r < 4; r++) {
        int mg2 = m0 + wm * 64 + mf * 16 + quad * 4 + r;
        unsigned b2 = (unsigned)mg2 / 3136u;
        unsigned p2 = (unsigned)mg2 - b2 * 3136u;
        out[(size_t)b2 * 802816u + (size_t)col * 3136u + p2] = acc[mf][nf][r] + bv;
      }
    }
  }
}

extern "C" void kernel_launch(void* const* d_in, const int* in_sizes, int n_in,
                              void* d_out, int out_size, void* d_ws, size_t ws_size,
                              hipStream_t stream) {
  (void)in_sizes; (void)n_in; (void)out_size; (void)ws_size;
  const float* inp  = (const float*)d_in[0];
  const float* w    = (const float*)d_in[1];
  const float* bias = (const float*)d_in[2];
  const int*   pm2  = (const int*)d_in[3];
  const int*   pcm  = (const int*)d_in[4];
  short* wbf = (short*)d_ws;            // 3,145,728 B used

  prep_w<<<6144, 256, 0, stream>>>(w, wbf);
  poly_gemm<<<dim3(98, 4), 256, 0, stream>>>(inp, wbf, bias, pm2, pcm, (float*)d_out);
}